// Round 17
// baseline (192.385 us; speedup 1.0000x reference)
//
#include <hip/hip_runtime.h>
#include <hip/hip_bf16.h>
#include <cstddef>

// SelfAttention local-window (K=7) module, MI355X.
// Split-bf16 GEMMs (v = hi + lo bf16 pair; W@X ~= Whi@Xhi + Whi@Xlo + Wlo@Xhi)
// + bf16 attention stage: QKV GEMM writes qkv as bf16 (single rounding),
// sim/ctx read bf16 -> K/V per batch (2.36 MB) fit a 4 MiB XCD L2, and the
// 49x tap re-reads halve in bytes.
// prep:        fold BN -> WeffHi/Lo, beff, wwHi/Lo
// tcvt<256>:   x fp32 -> xThi/xTlo bf16[b][HW][256]
// mfma<256>:   qkvH bf16[b][256][HW]  (3-segment split MFMA, fp32 accum)
// sim:         sim[b][49][HW] fp32   (bf16 Q,K reads)
// softmax:     in-place, masked, fp32
// ctx:         ctxf fp32[b][128][HW] (bf16 V reads)
// tcvt<128>:   ctxf -> ctxThi/Lo
// mfma<128>:   out = ww @ ctx + bw -> d_out fp32

#define HW 9216   // 96*96
#define IMH 96
#define IMW 96

using bf16x8 = __attribute__((ext_vector_type(8))) short;   // 8 bf16 in 4 VGPRs
using f32x4  = __attribute__((ext_vector_type(4))) float;   // MFMA accumulator

__device__ inline unsigned short f2bf(float f) {
  // round-to-nearest-even fp32 -> bf16
  unsigned u = __builtin_bit_cast(unsigned, f);
  unsigned r = 0x7fffu + ((u >> 16) & 1u);
  return (unsigned short)((u + r) >> 16);
}
__device__ inline float bf2f(unsigned short h) {
  unsigned u = (unsigned)h << 16;
  return __builtin_bit_cast(float, u);
}

__global__ __launch_bounds__(256) void prep_kernel(
    const float* __restrict__ wq, const float* __restrict__ bq,
    const float* __restrict__ gq, const float* __restrict__ betaq,
    const float* __restrict__ mq, const float* __restrict__ vq,
    const float* __restrict__ wk, const float* __restrict__ bk,
    const float* __restrict__ gk, const float* __restrict__ betak,
    const float* __restrict__ mk, const float* __restrict__ vk,
    const float* __restrict__ wv, const float* __restrict__ bv,
    const float* __restrict__ ww,
    unsigned short* __restrict__ WeffHi, unsigned short* __restrict__ WeffLo,
    float* __restrict__ beff,
    unsigned short* __restrict__ wwHi, unsigned short* __restrict__ wwLo) {
  int o = blockIdx.x;   // 0..255 output row
  int c = threadIdx.x;  // 0..255 input channel
  float wval, bval;
  if (o < 64) {
    float s = gq[o] * rsqrtf(vq[o] + 1e-5f);
    wval = wq[o * 256 + c] * s;
    bval = (bq[o] - mq[o]) * s + betaq[o];
  } else if (o < 128) {
    int oo = o - 64;
    float s = gk[oo] * rsqrtf(vk[oo] + 1e-5f);
    wval = wk[oo * 256 + c] * s;
    bval = (bk[oo] - mk[oo]) * s + betak[oo];
  } else {
    int oo = o - 128;
    wval = wv[oo * 256 + c];
    bval = bv[oo];
  }
  unsigned short hi = f2bf(wval);
  WeffHi[o * 256 + c] = hi;
  WeffLo[o * 256 + c] = f2bf(wval - bf2f(hi));
  if (c == 0) beff[o] = bval;
  if (c < 128) {
    float wv2 = ww[o * 128 + c];
    unsigned short h2 = f2bf(wv2);
    wwHi[o * 128 + c] = h2;
    wwLo[o * 128 + c] = f2bf(wv2 - bf2f(h2));
  }
}

// Transpose + fp32->bf16 hi/lo split: in[b][C][HW] -> hi/lo[b][HW][C]
template <int C>
__global__ __launch_bounds__(256) void tcvt_kernel(
    const float* __restrict__ in,
    unsigned short* __restrict__ outHi, unsigned short* __restrict__ outLo) {
  int b = blockIdx.z;
  int c0 = blockIdx.y * 64;
  int p0 = blockIdx.x * 64;
  const float* ib = in + (size_t)b * C * HW;
  unsigned short* obh = outHi + (size_t)b * HW * C;
  unsigned short* obl = outLo + (size_t)b * HW * C;
  __shared__ float t[64][65];
  int tid = threadIdx.x;
#pragma unroll
  for (int i = 0; i < 16; i++) {
    int idx = tid + i * 256;
    int c = idx >> 6, p = idx & 63;
    t[c][p] = ib[(size_t)(c0 + c) * HW + p0 + p];
  }
  __syncthreads();
#pragma unroll
  for (int i = 0; i < 16; i++) {
    int idx = tid + i * 256;
    int p = idx >> 6, c = idx & 63;
    float v = t[c][p];
    unsigned short hi = f2bf(v);
    size_t o = (size_t)(p0 + p) * C + c0 + c;
    obh[o] = hi;
    obl[o] = f2bf(v - bf2f(hi));
  }
}

// Split-bf16 MFMA GEMM: O[b][m][n] = sum_k W[m][k] * XT[b][n][k] + bias[m]
// 3 segments: (Whi,Xhi), (Whi,Xlo), (Wlo,Xhi) into the same fp32 accumulator.
// OUT_BF16: round epilogue to bf16 (qkv for the attn stage) else fp32 store.
// D-layout (m89-verified): lane l reg r -> i(n) = (l>>4)*4 + r, j(m) = l&15.
template <int KD, bool OUT_BF16>
__global__ __launch_bounds__(256) void mfma_gemm(
    const unsigned short* __restrict__ XThi,  // [b][HW][KD] bf16
    const unsigned short* __restrict__ XTlo,
    const unsigned short* __restrict__ WHhi,  // [256][KD]   bf16
    const unsigned short* __restrict__ WHlo,
    const float* __restrict__ bias,           // [256]
    void* __restrict__ Optr) {                // [b][256][HW] bf16 or fp32
  int b = blockIdx.z;
  int n0 = blockIdx.x * 128;
  int m0 = blockIdx.y * 128;
  const unsigned short* XbHi = XThi + (size_t)b * HW * KD;
  const unsigned short* XbLo = XTlo + (size_t)b * HW * KD;

  __shared__ unsigned short Xs[128][72];
  __shared__ unsigned short Ws[128][72];

  int tid = threadIdx.x;
  int wave = tid >> 6;
  int lane = tid & 63;
  int wn = (wave & 1) * 64;   // wave n-offset in tile
  int wm = (wave >> 1) * 64;  // wave m-offset in tile
  int l15 = lane & 15;
  int kg = lane >> 4;         // k-group 0..3

  f32x4 acc[4][4];            // [nf][mf]
#pragma unroll
  for (int i = 0; i < 4; i++)
#pragma unroll
    for (int j = 0; j < 4; j++) acc[i][j] = (f32x4){0.f, 0.f, 0.f, 0.f};

  for (int seg = 0; seg < 3; seg++) {
    const unsigned short* Xsrc = (seg == 1) ? XbLo : XbHi;
    const unsigned short* Wsrc = (seg == 2) ? WHlo : WHhi;
    for (int k0 = 0; k0 < KD; k0 += 64) {
#pragma unroll
      for (int i = 0; i < 4; i++) {
        int idx = tid + i * 256;          // 0..1023
        int r = idx >> 3, ch = idx & 7;   // row, 16B chunk
        *(int4*)&Xs[r][ch * 8] = *(const int4*)&Xsrc[(size_t)(n0 + r) * KD + k0 + ch * 8];
        *(int4*)&Ws[r][ch * 8] = *(const int4*)&Wsrc[(size_t)(m0 + r) * KD + k0 + ch * 8];
      }
      __syncthreads();
#pragma unroll
      for (int ks = 0; ks < 2; ks++) {
        bf16x8 a[4], w[4];
#pragma unroll
        for (int f = 0; f < 4; f++) {
          a[f] = *(const bf16x8*)&Xs[wn + f * 16 + l15][ks * 32 + kg * 8];
          w[f] = *(const bf16x8*)&Ws[wm + f * 16 + l15][ks * 32 + kg * 8];
        }
#pragma unroll
        for (int nf = 0; nf < 4; nf++)
#pragma unroll
          for (int mf = 0; mf < 4; mf++)
            acc[nf][mf] = __builtin_amdgcn_mfma_f32_16x16x32_bf16(
                a[nf], w[mf], acc[nf][mf], 0, 0, 0);
      }
      __syncthreads();
    }
  }

#pragma unroll
  for (int mf = 0; mf < 4; mf++) {
    int m = m0 + wm + mf * 16 + l15;
    float bs = bias[m];
#pragma unroll
    for (int nf = 0; nf < 4; nf++) {
      int n = n0 + wn + nf * 16 + kg * 4;
      f32x4 v = acc[nf][mf];
      if constexpr (OUT_BF16) {
        unsigned short* Ob = (unsigned short*)Optr + (size_t)b * 256 * HW;
        ushort4 s4;
        s4.x = f2bf(v[0] + bs); s4.y = f2bf(v[1] + bs);
        s4.z = f2bf(v[2] + bs); s4.w = f2bf(v[3] + bs);
        *(ushort4*)&Ob[(size_t)m * HW + n] = s4;
      } else {
        float* Ob = (float*)Optr + (size_t)b * 256 * HW;
        float4 r4;
        r4.x = v[0] + bs; r4.y = v[1] + bs; r4.z = v[2] + bs; r4.w = v[3] + bs;
        *(float4*)&Ob[(size_t)m * HW + n] = r4;
      }
    }
  }
}

// sim[b][tap][pix] = valid ? sum_c Q[c,pix]*K[c,pix+off] : 0   (bf16 Q,K)
__global__ __launch_bounds__(64) void sim_kernel(
    const unsigned short* __restrict__ qkvH, float* __restrict__ sm) {
  int b = blockIdx.z;
  int tap = blockIdx.y;                    // 0..48
  int pix = blockIdx.x * 64 + threadIdx.x;
  int h = pix / IMW, w = pix % IMW;
  int di = tap / 7 - 3, dj = tap % 7 - 3;
  const unsigned short* Qp = qkvH + (size_t)b * 256 * HW + pix;
  const unsigned short* Kp = Qp + (size_t)64 * HW + di * IMW + dj;

  float a0 = 0.f, a1 = 0.f, a2 = 0.f, a3 = 0.f;
#pragma unroll 8
  for (int c = 0; c < 64; c++) {
    float q = bf2f(Qp[(size_t)c * HW]);
    float k = bf2f(Kp[(size_t)c * HW]);
    if ((c & 3) == 0) a0 = fmaf(q, k, a0);
    else if ((c & 3) == 1) a1 = fmaf(q, k, a1);
    else if ((c & 3) == 2) a2 = fmaf(q, k, a2);
    else a3 = fmaf(q, k, a3);
  }
  float s = (a0 + a1) + (a2 + a3);
  bool valid = ((unsigned)(h + di) < (unsigned)IMH) &&
               ((unsigned)(w + dj) < (unsigned)IMW);
  sm[((size_t)b * 49 + tap) * HW + pix] = valid ? s : 0.f;
}

// In-place masked softmax over the 49 taps (fp32).
__global__ __launch_bounds__(64) void softmax_kernel(float* __restrict__ sm) {
  int b = blockIdx.y;
  int pix = blockIdx.x * 64 + threadIdx.x;
  int h = pix / IMW, w = pix % IMW;
  float* S = sm + (size_t)b * 49 * HW + pix;

  float v[49];
#pragma unroll
  for (int p = 0; p < 49; p++) v[p] = S[(size_t)p * HW];

  float mx = v[0];
#pragma unroll
  for (int p = 1; p < 49; p++) mx = fmaxf(mx, v[p]);
  float ssum = 0.f;
#pragma unroll
  for (int p = 0; p < 49; p++) {
    v[p] = __expf(v[p] - mx);
    ssum += v[p];
  }
  float inv = 1.f / ssum;
#pragma unroll
  for (int p = 0; p < 49; p++) {
    const int di = p / 7 - 3, dj = p % 7 - 3;
    bool valid = ((unsigned)(h + di) < (unsigned)IMH) &&
                 ((unsigned)(w + dj) < (unsigned)IMW);
    S[(size_t)p * HW] = valid ? v[p] * inv : 0.f;
  }
}

// ctxf[b][c][pix] = sum_p sm[p][pix] * V[c][pix+off_p]   (bf16 V)
__global__ __launch_bounds__(64) void ctx_kernel(
    const unsigned short* __restrict__ qkvH, const float* __restrict__ sm,
    float* __restrict__ ctx) {
  int b = blockIdx.z;
  int c0 = blockIdx.y * 4;
  int pix = blockIdx.x * 64 + threadIdx.x;

  const float* S = sm + (size_t)b * 49 * HW + pix;
  float p[49];
#pragma unroll
  for (int t = 0; t < 49; t++) p[t] = S[(size_t)t * HW];

  const unsigned short* V = qkvH + ((size_t)b * 256 + 128) * HW + pix;
  float* Cb = ctx + (size_t)b * 128 * HW + pix;

#pragma unroll
  for (int cc = 0; cc < 4; cc++) {
    const unsigned short* Vc = V + (size_t)(c0 + cc) * HW;
    float a0 = 0.f, a1 = 0.f, a2 = 0.f, a3 = 0.f;
#pragma unroll
    for (int t = 0; t < 49; t++) {
      const int di = t / 7 - 3, dj = t % 7 - 3;
      float v = bf2f(Vc[di * IMW + dj]);
      if ((t & 3) == 0) a0 = fmaf(p[t], v, a0);
      else if ((t & 3) == 1) a1 = fmaf(p[t], v, a1);
      else if ((t & 3) == 2) a2 = fmaf(p[t], v, a2);
      else a3 = fmaf(p[t], v, a3);
    }
    Cb[(size_t)(c0 + cc) * HW] = (a0 + a1) + (a2 + a3);
  }
}

extern "C" void kernel_launch(void* const* d_in, const int* in_sizes, int n_in,
                              void* d_out, int out_size, void* d_ws, size_t ws_size,
                              hipStream_t stream) {
  const float* x     = (const float*)d_in[0];
  const float* wq    = (const float*)d_in[1];
  const float* bq    = (const float*)d_in[2];
  const float* gq    = (const float*)d_in[3];
  const float* betaq = (const float*)d_in[4];
  const float* mq    = (const float*)d_in[5];
  const float* vq    = (const float*)d_in[6];
  const float* wk    = (const float*)d_in[7];
  const float* bk    = (const float*)d_in[8];
  const float* gk    = (const float*)d_in[9];
  const float* betak = (const float*)d_in[10];
  const float* mk    = (const float*)d_in[11];
  const float* vk    = (const float*)d_in[12];
  const float* wv    = (const float*)d_in[13];
  const float* bv    = (const float*)d_in[14];
  const float* ww    = (const float*)d_in[15];
  const float* bw    = (const float*)d_in[16];

  char* base = (char*)d_ws;
  unsigned short* WeffHi = (unsigned short*)(base + 0);         // 131072 B
  unsigned short* WeffLo = (unsigned short*)(base + 131072);    // 131072 B
  unsigned short* wwHi   = (unsigned short*)(base + 262144);    // 65536 B
  unsigned short* wwLo   = (unsigned short*)(base + 327680);    // 65536 B
  float*          beff   = (float*)(base + 393216);             // 1024 B
  unsigned short* xThi   = (unsigned short*)(base + 397312);    // 9437184 B
  unsigned short* xTlo   = (unsigned short*)(base + 9834496);   // 9437184 B
  unsigned short* qkvH   = (unsigned short*)(base + 19271680);  // 9437184 B
  // 4096 B guard after qkvH: masked tail reads (pix+291, ch 255) land here
  float*          smb    = (float*)(base + 28712960);           // 3612672 B
  float*          ctxf   = (float*)(base + 32325632);           // 9437184 B
  unsigned short* ctxThi = (unsigned short*)(base + 41762816);  // 4718592 B
  unsigned short* ctxTlo = (unsigned short*)(base + 46481408);  // 4718592 B

  prep_kernel<<<dim3(256), dim3(256), 0, stream>>>(
      wq, bq, gq, betaq, mq, vq, wk, bk, gk, betak, mk, vk, wv, bv, ww,
      WeffHi, WeffLo, beff, wwHi, wwLo);

  tcvt_kernel<256><<<dim3(144, 4, 2), dim3(256), 0, stream>>>(x, xThi, xTlo);

  mfma_gemm<256, true><<<dim3(72, 2, 2), dim3(256), 0, stream>>>(
      xThi, xTlo, WeffHi, WeffLo, beff, qkvH);

  sim_kernel<<<dim3(144, 49, 2), dim3(64), 0, stream>>>(qkvH, smb);

  softmax_kernel<<<dim3(144, 2), dim3(64), 0, stream>>>(smb);

  ctx_kernel<<<dim3(144, 32, 2), dim3(64), 0, stream>>>(qkvH, smb, ctxf);

  tcvt_kernel<128><<<dim3(144, 2, 2), dim3(256), 0, stream>>>(ctxf, ctxThi, ctxTlo);

  mfma_gemm<128, false><<<dim3(72, 2, 2), dim3(256), 0, stream>>>(
      ctxThi, ctxTlo, wwHi, wwLo, bw, (float*)d_out);
}